// Round 7
// baseline (624.827 us; speedup 1.0000x reference)
//
#include <hip/hip_runtime.h>

#define N_NODES 100000
#define VROWS   200000          // virtual rows: [0,100000)=feat, [100000,200000)=adj
#define NGROUP  8               // XCD count (blockIdx%8 -> XCD heuristic)
#define BSHIFT  8
#define BROWS   256             // rows per bucket
#define NBUCK   ((VROWS + BROWS - 1) / BROWS)   // 782
#define SUBCAP  1024            // staged elems per (bucket,group); mean 576, std ~24

static __device__ __forceinline__ unsigned short f2bf(float x) {
    unsigned u = __float_as_uint(x);
    return (unsigned short)((u + 0x7fffu + ((u >> 16) & 1u)) >> 16);
}

// nt load of a packed (col,val) element via long long (builtin rejects HIP vector types)
static __device__ __forceinline__ void nt_colval(const long long* p, int& c, float& v) {
    long long e = __builtin_nontemporal_load(p);
    c = (int)(e & 0xffffffffLL);
    v = __uint_as_float((unsigned)((unsigned long long)e >> 32));
}

// ---------------- CSR build: 2-phase bucket sort ----------------

__global__ void zero_int_kernel(int* __restrict__ p, int n) {
    int i = blockIdx.x * blockDim.x + threadIdx.x;
    if (i < n) p[i] = 0;
}

// Phase A: single-pass binning of ROW INDICES ONLY (4B payload = rowlocal|flag|idx).
// 4-way unroll: 4 independent load->atomicAdd->store chains per thread to hide
// atomic round-trip latency (the R6 bottleneck: 1 outstanding atomic per wave).
__global__ __launch_bounds__(256) void bin_kernel(
        const int* __restrict__ f_rows, const int* __restrict__ a_rows,
        int* __restrict__ cur, unsigned* __restrict__ staging, int nnzf, int nedge) {
    const int g = blockIdx.x & (NGROUP - 1);
    const int stride = gridDim.x * 256;
    int i = blockIdx.x * 256 + (int)threadIdx.x;
    // ---- feat elements: payload idx | (rowlocal<<24) ----
    for (; i + 3 * stride < nnzf; i += 4 * stride) {
        const int i0 = i, i1 = i + stride, i2 = i + 2 * stride, i3 = i + 3 * stride;
        const int r0 = __builtin_nontemporal_load(f_rows + i0);
        const int r1 = __builtin_nontemporal_load(f_rows + i1);
        const int r2 = __builtin_nontemporal_load(f_rows + i2);
        const int r3 = __builtin_nontemporal_load(f_rows + i3);
        const int p0 = atomicAdd(&cur[(r0 >> BSHIFT) * NGROUP + g], 1);
        const int p1 = atomicAdd(&cur[(r1 >> BSHIFT) * NGROUP + g], 1);
        const int p2 = atomicAdd(&cur[(r2 >> BSHIFT) * NGROUP + g], 1);
        const int p3 = atomicAdd(&cur[(r3 >> BSHIFT) * NGROUP + g], 1);
        if (p0 < SUBCAP) staging[(size_t)((r0 >> BSHIFT) * NGROUP + g) * SUBCAP + p0] = (unsigned)i0 | ((unsigned)(r0 & 255) << 24);
        if (p1 < SUBCAP) staging[(size_t)((r1 >> BSHIFT) * NGROUP + g) * SUBCAP + p1] = (unsigned)i1 | ((unsigned)(r1 & 255) << 24);
        if (p2 < SUBCAP) staging[(size_t)((r2 >> BSHIFT) * NGROUP + g) * SUBCAP + p2] = (unsigned)i2 | ((unsigned)(r2 & 255) << 24);
        if (p3 < SUBCAP) staging[(size_t)((r3 >> BSHIFT) * NGROUP + g) * SUBCAP + p3] = (unsigned)i3 | ((unsigned)(r3 & 255) << 24);
    }
    for (; i < nnzf; i += stride) {
        const int r = __builtin_nontemporal_load(f_rows + i);
        const int p = atomicAdd(&cur[(r >> BSHIFT) * NGROUP + g], 1);
        if (p < SUBCAP) staging[(size_t)((r >> BSHIFT) * NGROUP + g) * SUBCAP + p] = (unsigned)i | ((unsigned)(r & 255) << 24);
    }
    // ---- adj elements: payload idx | isadj | rowlocal (virtual row = a_row + N_NODES) ----
    i = blockIdx.x * 256 + (int)threadIdx.x;
    for (; i + 3 * stride < nedge; i += 4 * stride) {
        const int i0 = i, i1 = i + stride, i2 = i + 2 * stride, i3 = i + 3 * stride;
        const int r0 = __builtin_nontemporal_load(a_rows + i0) + N_NODES;
        const int r1 = __builtin_nontemporal_load(a_rows + i1) + N_NODES;
        const int r2 = __builtin_nontemporal_load(a_rows + i2) + N_NODES;
        const int r3 = __builtin_nontemporal_load(a_rows + i3) + N_NODES;
        const int p0 = atomicAdd(&cur[(r0 >> BSHIFT) * NGROUP + g], 1);
        const int p1 = atomicAdd(&cur[(r1 >> BSHIFT) * NGROUP + g], 1);
        const int p2 = atomicAdd(&cur[(r2 >> BSHIFT) * NGROUP + g], 1);
        const int p3 = atomicAdd(&cur[(r3 >> BSHIFT) * NGROUP + g], 1);
        if (p0 < SUBCAP) staging[(size_t)((r0 >> BSHIFT) * NGROUP + g) * SUBCAP + p0] = (unsigned)i0 | 0x800000u | ((unsigned)(r0 & 255) << 24);
        if (p1 < SUBCAP) staging[(size_t)((r1 >> BSHIFT) * NGROUP + g) * SUBCAP + p1] = (unsigned)i1 | 0x800000u | ((unsigned)(r1 & 255) << 24);
        if (p2 < SUBCAP) staging[(size_t)((r2 >> BSHIFT) * NGROUP + g) * SUBCAP + p2] = (unsigned)i2 | 0x800000u | ((unsigned)(r2 & 255) << 24);
        if (p3 < SUBCAP) staging[(size_t)((r3 >> BSHIFT) * NGROUP + g) * SUBCAP + p3] = (unsigned)i3 | 0x800000u | ((unsigned)(r3 & 255) << 24);
    }
    for (; i < nedge; i += stride) {
        const int r = __builtin_nontemporal_load(a_rows + i) + N_NODES;
        const int p = atomicAdd(&cur[(r >> BSHIFT) * NGROUP + g], 1);
        if (p < SUBCAP) staging[(size_t)((r >> BSHIFT) * NGROUP + g) * SUBCAP + p] = (unsigned)i | 0x800000u | ((unsigned)(r & 255) << 24);
    }
}

// Bucket-level exclusive scan (1 block, 1024 threads; NBUCK=782 fits).
__global__ void bucket_scan_kernel(const int* __restrict__ cur, int* __restrict__ bases,
                                   int* __restrict__ rp) {
    __shared__ int sh[1024];
    const int t = threadIdx.x;
    int tot = 0;
    if (t < NBUCK) {
        #pragma unroll
        for (int g = 0; g < NGROUP; ++g) tot += min(cur[t * NGROUP + g], SUBCAP);
    }
    sh[t] = tot;
    __syncthreads();
    for (int off = 1; off < 1024; off <<= 1) {
        int u = (t >= off) ? sh[t - off] : 0;
        __syncthreads();
        sh[t] += u;
        __syncthreads();
    }
    if (t < NBUCK) bases[t] = sh[t] - tot;      // exclusive prefix
    if (t == NBUCK - 1) rp[VROWS] = sh[t];      // grand total sentinel
}

// Phase B: one block per bucket. Stream the 8 staged sub-segments twice:
// count rows in LDS -> 256-wide scan -> write row_ptr -> place into final colval,
// fetching (col,val) from the source COO arrays by staged index.
__global__ __launch_bounds__(256) void sort_kernel(
        const int* __restrict__ cur, const int* __restrict__ bases,
        const unsigned* __restrict__ staging,
        const int* __restrict__ f_cols, const float* __restrict__ f_vals,
        const int* __restrict__ a_cols, const float* __restrict__ a_vals,
        long long* __restrict__ colval, int* __restrict__ rp) {
    const int b = blockIdx.x;
    const int t = threadIdx.x;
    __shared__ int cnt[BROWS];
    __shared__ int offs[BROWS];
    __shared__ int segc[NGROUP];
    cnt[t] = 0;
    if (t < NGROUP) segc[t] = min(cur[b * NGROUP + t], SUBCAP);
    __syncthreads();
    const unsigned* sbase = staging + (size_t)b * NGROUP * SUBCAP;
    // pass 1: count rows
    for (int g = 0; g < NGROUP; ++g) {
        const int n = segc[g];
        const unsigned* seg = sbase + (size_t)g * SUBCAP;
        for (int j = t; j < n; j += 256) {
            atomicAdd(&cnt[seg[j] >> 24], 1);
        }
    }
    __syncthreads();
    // exclusive scan of cnt (Hillis-Steele over 256)
    int v = cnt[t];
    offs[t] = v;
    __syncthreads();
    for (int o = 1; o < BROWS; o <<= 1) {
        int u = (t >= o) ? offs[t - o] : 0;
        __syncthreads();
        offs[t] += u;
        __syncthreads();
    }
    const int excl = offs[t] - v;    // each thread reads only its own slot
    offs[t] = excl;                  // becomes the placement cursor
    const int base = bases[b];
    const int row = (b << BSHIFT) + t;
    if (row < VROWS) rp[row] = base + excl;
    __syncthreads();
    // pass 2: place, gathering (col,val) from source arrays by idx
    for (int g = 0; g < NGROUP; ++g) {
        const int n = segc[g];
        const unsigned* seg = sbase + (size_t)g * SUBCAP;
        for (int j = t; j < n; j += 256) {
            const unsigned w = seg[j];
            const int rl  = w >> 24;
            const int idx = w & 0x7fffff;
            const int*   cb = (w & 0x800000u) ? a_cols : f_cols;
            const float* vb = (w & 0x800000u) ? a_vals : f_vals;
            const int   c = cb[idx];
            const float x = vb[idx];
            const int p = atomicAdd(&offs[rl], 1);
            colval[base + p] = (long long)(unsigned)c | ((long long)(unsigned)__float_as_uint(x) << 32);
        }
    }
}

// ---------------- SpMM: sparse [N,512] @ W[512,128] + bias + relu -> bf16 base ----------------
// One wave per row; each lane owns a float2 slice of the 128 outputs.

__global__ __launch_bounds__(256) void spmm_feat_kernel(
        const int* __restrict__ row_ptr, const long long* __restrict__ colval,
        const float* __restrict__ W, const float* __restrict__ bias,
        unsigned short* __restrict__ base_bf, int n) {
    const int wave = (blockIdx.x * blockDim.x + threadIdx.x) >> 6;
    const int lane = threadIdx.x & 63;
    if (wave >= n) return;
    const int beg = row_ptr[wave];
    const int end = row_ptr[wave + 1];
    const float2* __restrict__ W2 = (const float2*)W;
    float2 a0 = make_float2(0.f, 0.f), a1 = a0, a2 = a0, a3 = a0;
    int i = beg;
    for (; i + 3 < end; i += 4) {
        int c0, c1, c2, c3; float v0, v1, v2, v3;
        nt_colval(colval + i,     c0, v0);
        nt_colval(colval + i + 1, c1, v1);
        nt_colval(colval + i + 2, c2, v2);
        nt_colval(colval + i + 3, c3, v3);
        const float2 w0 = W2[c0 * 64 + lane];
        const float2 w1 = W2[c1 * 64 + lane];
        const float2 w2 = W2[c2 * 64 + lane];
        const float2 w3 = W2[c3 * 64 + lane];
        a0.x += v0 * w0.x; a0.y += v0 * w0.y;
        a1.x += v1 * w1.x; a1.y += v1 * w1.y;
        a2.x += v2 * w2.x; a2.y += v2 * w2.y;
        a3.x += v3 * w3.x; a3.y += v3 * w3.y;
    }
    for (; i < end; ++i) {
        int c; float v;
        nt_colval(colval + i, c, v);
        const float2 w = W2[c * 64 + lane];
        a0.x += v * w.x; a0.y += v * w.y;
    }
    const float2 b = ((const float2*)bias)[lane];
    float ax = fmaxf((a0.x + a1.x) + (a2.x + a3.x) + b.x, 0.f);
    float ay = fmaxf((a0.y + a1.y) + (a2.y + a3.y) + b.y, 0.f);
    ushort2 o;
    o.x = f2bf(ax);
    o.y = f2bf(ay);
    ((ushort2*)base_bf)[wave * 64 + lane] = o;
}

// ---------------- adjacency pass: dst = A @ src, bf16 in / bf16 out ----------------

__global__ __launch_bounds__(256) void spmm_adj_bf_bf_kernel(
        const int* __restrict__ row_ptr, const long long* __restrict__ colval,
        const unsigned* __restrict__ src, unsigned short* __restrict__ dst, int n) {
    const int wave = (blockIdx.x * blockDim.x + threadIdx.x) >> 6;
    const int lane = threadIdx.x & 63;
    if (wave >= n) return;
    const int beg = row_ptr[wave];
    const int end = row_ptr[wave + 1];
    float2 a0 = make_float2(0.f, 0.f), a1 = a0, a2 = a0, a3 = a0;
    int i = beg;
    for (; i + 3 < end; i += 4) {
        int c0, c1, c2, c3; float v0, v1, v2, v3;
        nt_colval(colval + i,     c0, v0);
        nt_colval(colval + i + 1, c1, v1);
        nt_colval(colval + i + 2, c2, v2);
        nt_colval(colval + i + 3, c3, v3);
        const unsigned s0 = src[c0 * 64 + lane];
        const unsigned s1 = src[c1 * 64 + lane];
        const unsigned s2 = src[c2 * 64 + lane];
        const unsigned s3 = src[c3 * 64 + lane];
        a0.x += v0 * __uint_as_float(s0 << 16); a0.y += v0 * __uint_as_float(s0 & 0xffff0000u);
        a1.x += v1 * __uint_as_float(s1 << 16); a1.y += v1 * __uint_as_float(s1 & 0xffff0000u);
        a2.x += v2 * __uint_as_float(s2 << 16); a2.y += v2 * __uint_as_float(s2 & 0xffff0000u);
        a3.x += v3 * __uint_as_float(s3 << 16); a3.y += v3 * __uint_as_float(s3 & 0xffff0000u);
    }
    for (; i < end; ++i) {
        int c; float v;
        nt_colval(colval + i, c, v);
        const unsigned s = src[c * 64 + lane];
        a0.x += v * __uint_as_float(s << 16); a0.y += v * __uint_as_float(s & 0xffff0000u);
    }
    float ax = (a0.x + a1.x) + (a2.x + a3.x);
    float ay = (a0.y + a1.y) + (a2.y + a3.y);
    ushort2 o;
    o.x = f2bf(ax);
    o.y = f2bf(ay);
    ((ushort2*)dst)[wave * 64 + lane] = o;
}

// ---------------- adjacency pass: dst = A @ src, bf16 in / f32 out ----------------

__global__ __launch_bounds__(256) void spmm_adj_bf_f32_kernel(
        const int* __restrict__ row_ptr, const long long* __restrict__ colval,
        const unsigned* __restrict__ src, float* __restrict__ dst, int n) {
    const int wave = (blockIdx.x * blockDim.x + threadIdx.x) >> 6;
    const int lane = threadIdx.x & 63;
    if (wave >= n) return;
    const int beg = row_ptr[wave];
    const int end = row_ptr[wave + 1];
    float2 a0 = make_float2(0.f, 0.f), a1 = a0, a2 = a0, a3 = a0;
    int i = beg;
    for (; i + 3 < end; i += 4) {
        int c0, c1, c2, c3; float v0, v1, v2, v3;
        nt_colval(colval + i,     c0, v0);
        nt_colval(colval + i + 1, c1, v1);
        nt_colval(colval + i + 2, c2, v2);
        nt_colval(colval + i + 3, c3, v3);
        const unsigned s0 = src[c0 * 64 + lane];
        const unsigned s1 = src[c1 * 64 + lane];
        const unsigned s2 = src[c2 * 64 + lane];
        const unsigned s3 = src[c3 * 64 + lane];
        a0.x += v0 * __uint_as_float(s0 << 16); a0.y += v0 * __uint_as_float(s0 & 0xffff0000u);
        a1.x += v1 * __uint_as_float(s1 << 16); a1.y += v1 * __uint_as_float(s1 & 0xffff0000u);
        a2.x += v2 * __uint_as_float(s2 << 16); a2.y += v2 * __uint_as_float(s2 & 0xffff0000u);
        a3.x += v3 * __uint_as_float(s3 << 16); a3.y += v3 * __uint_as_float(s3 & 0xffff0000u);
    }
    for (; i < end; ++i) {
        int c; float v;
        nt_colval(colval + i, c, v);
        const unsigned s = src[c * 64 + lane];
        a0.x += v * __uint_as_float(s << 16); a0.y += v * __uint_as_float(s & 0xffff0000u);
    }
    float2 acc;
    acc.x = (a0.x + a1.x) + (a2.x + a3.x);
    acc.y = (a0.y + a1.y) + (a2.y + a3.y);
    ((float2*)dst)[wave * 64 + lane] = acc;
}

// ---------------- launch ----------------

extern "C" void kernel_launch(void* const* d_in, const int* in_sizes, int n_in,
                              void* d_out, int out_size, void* d_ws, size_t ws_size,
                              hipStream_t stream) {
    const int*   fi   = (const int*)d_in[0];     // feat_indices [2, nnzf]
    const float* fv   = (const float*)d_in[1];   // feat_values  [nnzf]
    const int*   ai   = (const int*)d_in[2];     // adj_indices  [2, nedge]
    const float* av   = (const float*)d_in[3];   // adj_values   [nedge]
    const float* W    = (const float*)d_in[4];   // weight [512,128]
    const float* bias = (const float*)d_in[5];   // bias [1,128]
    float* out = (float*)d_out;

    const int nnzf  = in_sizes[1];
    const int nedge = in_sizes[3];
    const int ntot  = nnzf + nedge;
    const int* f_rows = fi;
    const int* f_cols = fi + nnzf;
    const int* a_rows = ai;
    const int* a_cols = ai + nedge;

    // bump-allocate workspace (256B aligned)
    char* wp = (char*)d_ws;
    auto balloc = [&](size_t bytes) -> char* {
        char* p = wp;
        wp += (bytes + 255) & ~(size_t)255;
        return p;
    };
    // staging (25.6MB, 4B/slot) dead after sort; base_bf (25.6MB) overlays it.
    unsigned* staging = (unsigned*)balloc(4ull * NBUCK * NGROUP * SUBCAP);
    unsigned short* base_bf = (unsigned short*)staging;
    unsigned short* t1 = (unsigned short*)balloc(2ull * N_NODES * 128);
    long long* colval = (long long*)balloc(8ull * (size_t)ntot);
    int* rp    = (int*)balloc(4ull * (VROWS + 1));
    int* cur   = (int*)balloc(4ull * NBUCK * NGROUP);
    int* bases = (int*)balloc(4ull * NBUCK);

    const int NCELL = NBUCK * NGROUP;
    const int RW = (N_NODES + 3) / 4;    // 4 waves (rows) per 256-thread block

    // ---- CSR build: bin -> bucket scan -> per-bucket sort ----
    zero_int_kernel<<<(NCELL + 255) / 256, 256, 0, stream>>>(cur, NCELL);
    bin_kernel<<<2048, 256, 0, stream>>>(f_rows, a_rows, cur, staging, nnzf, nedge);
    bucket_scan_kernel<<<1, 1024, 0, stream>>>(cur, bases, rp);
    sort_kernel<<<NBUCK, 256, 0, stream>>>(cur, bases, staging,
                                           f_cols, fv, a_cols, av, colval, rp);

    // ---- compute: feat -> base_bf(bf16), adj -> t1(bf16), adj -> out(f32) ----
    spmm_feat_kernel<<<RW, 256, 0, stream>>>(rp, colval, W, bias, base_bf, N_NODES);
    spmm_adj_bf_bf_kernel<<<RW, 256, 0, stream>>>(rp + N_NODES, colval,
                                                  (const unsigned*)base_bf, t1, N_NODES);
    spmm_adj_bf_f32_kernel<<<RW, 256, 0, stream>>>(rp + N_NODES, colval,
                                                   (const unsigned*)t1, out, N_NODES);
}

// Round 8
// 375.267 us; speedup vs baseline: 1.6650x; 1.6650x over previous
//
#include <hip/hip_runtime.h>

#define N_NODES 100000
#define VROWS   200000          // virtual rows: [0,100000)=feat, [100000,200000)=adj
#define BSHIFT  8
#define BROWS   256             // rows per bucket
#define NBUCK   ((VROWS + BROWS - 1) / BROWS)   // 782
#define BINB    256             // blocks for binA/binB

static __device__ __forceinline__ unsigned short f2bf(float x) {
    unsigned u = __float_as_uint(x);
    return (unsigned short)((u + 0x7fffu + ((u >> 16) & 1u)) >> 16);
}

// nt load of a packed (col,val) element via long long (builtin rejects HIP vector types)
static __device__ __forceinline__ void nt_colval(const long long* p, int& c, float& v) {
    long long e = __builtin_nontemporal_load(p);
    c = (int)(e & 0x1ffffLL);
    v = __uint_as_float((unsigned)((unsigned long long)e >> 32));
}

// payload: lo = col(17b) | rowlocal(8b)<<17 ; hi = val bits
static __device__ __forceinline__ long long pack_cv(int col, int rl, float v) {
    unsigned lo = (unsigned)col | ((unsigned)rl << 17);
    return (long long)lo | ((long long)(unsigned)__float_as_uint(v) << 32);
}

// ---------------- CSR build: atomic-light two-pass multisplit ----------------

__global__ void zero_small_kernel(int* __restrict__ p, int n) {
    int i = blockIdx.x * blockDim.x + threadIdx.x;
    if (i < n) p[i] = 0;
}

// Pass A: per-block LDS histogram over buckets; ONE global atomic per (block,bucket).
__global__ __launch_bounds__(256) void binA_kernel(
        const int* __restrict__ f_rows, const int* __restrict__ a_rows,
        int* __restrict__ cur, int* __restrict__ pbb, int nnzf, int nedge) {
    __shared__ int hist[NBUCK];
    const int t = threadIdx.x;
    for (int b = t; b < NBUCK; b += 256) hist[b] = 0;
    __syncthreads();
    // feat chunk
    {
        const int per = (nnzf + BINB - 1) / BINB;
        const int beg = blockIdx.x * per;
        const int end = min(beg + per, nnzf);
        int i = beg + t;
        for (; i + 3 * 256 < end; i += 4 * 256) {
            int r0 = f_rows[i], r1 = f_rows[i + 256], r2 = f_rows[i + 512], r3 = f_rows[i + 768];
            atomicAdd(&hist[r0 >> BSHIFT], 1);
            atomicAdd(&hist[r1 >> BSHIFT], 1);
            atomicAdd(&hist[r2 >> BSHIFT], 1);
            atomicAdd(&hist[r3 >> BSHIFT], 1);
        }
        for (; i < end; i += 256) atomicAdd(&hist[f_rows[i] >> BSHIFT], 1);
    }
    // adj chunk (virtual rows +N_NODES)
    {
        const int per = (nedge + BINB - 1) / BINB;
        const int beg = blockIdx.x * per;
        const int end = min(beg + per, nedge);
        int i = beg + t;
        for (; i + 3 * 256 < end; i += 4 * 256) {
            int r0 = a_rows[i] + N_NODES, r1 = a_rows[i + 256] + N_NODES;
            int r2 = a_rows[i + 512] + N_NODES, r3 = a_rows[i + 768] + N_NODES;
            atomicAdd(&hist[r0 >> BSHIFT], 1);
            atomicAdd(&hist[r1 >> BSHIFT], 1);
            atomicAdd(&hist[r2 >> BSHIFT], 1);
            atomicAdd(&hist[r3 >> BSHIFT], 1);
        }
        for (; i < end; i += 256) atomicAdd(&hist[(a_rows[i] + N_NODES) >> BSHIFT], 1);
    }
    __syncthreads();
    for (int b = t; b < NBUCK; b += 256) {
        int c = hist[b];
        pbb[blockIdx.x * NBUCK + b] = c ? atomicAdd(&cur[b], c) : 0;
    }
}

// Exclusive scan of 782 bucket counts -> bbase; rp[VROWS] = total.
__global__ void bucket_scan_kernel(const int* __restrict__ cur, int* __restrict__ bbase,
                                   int* __restrict__ rp) {
    __shared__ int sh[1024];
    const int t = threadIdx.x;
    int v = (t < NBUCK) ? cur[t] : 0;
    sh[t] = v;
    __syncthreads();
    for (int off = 1; off < 1024; off <<= 1) {
        int u = (t >= off) ? sh[t - off] : 0;
        __syncthreads();
        sh[t] += u;
        __syncthreads();
    }
    if (t < NBUCK) bbase[t] = sh[t] - v;
    if (t == NBUCK - 1) rp[VROWS] = sh[t];
}

// Pass B: replay chunk; place payloads at bbase[b] + pbb[block][b] + ldscursor.
// Each (block,bucket) staging region is written exclusively by this block,
// temporally clustered -> full 64B line assembly in the local L2.
__global__ __launch_bounds__(256) void binB_kernel(
        const int* __restrict__ f_rows, const int* __restrict__ f_cols, const float* __restrict__ f_vals,
        const int* __restrict__ a_rows, const int* __restrict__ a_cols, const float* __restrict__ a_vals,
        const int* __restrict__ bbase, const int* __restrict__ pbb,
        long long* __restrict__ staging, int nnzf, int nedge) {
    __shared__ int curs[NBUCK];
    const int t = threadIdx.x;
    for (int b = t; b < NBUCK; b += 256) curs[b] = bbase[b] + pbb[blockIdx.x * NBUCK + b];
    __syncthreads();
    // feat chunk
    {
        const int per = (nnzf + BINB - 1) / BINB;
        const int beg = blockIdx.x * per;
        const int end = min(beg + per, nnzf);
        for (int i = beg + t; i < end; i += 256) {
            const int   r = f_rows[i];
            const int   c = f_cols[i];
            const float v = f_vals[i];
            const int p = atomicAdd(&curs[r >> BSHIFT], 1);
            staging[p] = pack_cv(c, r & (BROWS - 1), v);
        }
    }
    // adj chunk
    {
        const int per = (nedge + BINB - 1) / BINB;
        const int beg = blockIdx.x * per;
        const int end = min(beg + per, nedge);
        for (int i = beg + t; i < end; i += 256) {
            const int   r = a_rows[i] + N_NODES;
            const int   c = a_cols[i];
            const float v = a_vals[i];
            const int p = atomicAdd(&curs[r >> BSHIFT], 1);
            staging[p] = pack_cv(c, r & (BROWS - 1), v);
        }
    }
}

// Per-bucket sort: count rows in LDS -> scan -> row_ptr -> place into colval.
__global__ __launch_bounds__(256) void sort_kernel(
        const int* __restrict__ cur, const int* __restrict__ bbase,
        const long long* __restrict__ staging, long long* __restrict__ colval,
        int* __restrict__ rp) {
    const int b = blockIdx.x;
    const int t = threadIdx.x;
    __shared__ int cnt[BROWS];
    __shared__ int offs[BROWS];
    cnt[t] = 0;
    __syncthreads();
    const int n = cur[b];
    const int base = bbase[b];
    const long long* seg = staging + base;
    for (int j = t; j < n; j += 256) {
        unsigned lo = (unsigned)(seg[j] & 0xffffffffLL);
        atomicAdd(&cnt[(lo >> 17) & (BROWS - 1)], 1);
    }
    __syncthreads();
    int v = cnt[t];
    offs[t] = v;
    __syncthreads();
    for (int o = 1; o < BROWS; o <<= 1) {
        int u = (t >= o) ? offs[t - o] : 0;
        __syncthreads();
        offs[t] += u;
        __syncthreads();
    }
    const int excl = offs[t] - v;
    offs[t] = base + excl;           // absolute placement cursor
    const int row = (b << BSHIFT) + t;
    if (row < VROWS) rp[row] = base + excl;
    __syncthreads();
    for (int j = t; j < n; j += 256) {
        long long e = seg[j];
        unsigned lo = (unsigned)(e & 0xffffffffLL);
        const int rl = (lo >> 17) & (BROWS - 1);
        const int p = atomicAdd(&offs[rl], 1);
        colval[p] = (long long)(lo & 0x1ffffu) | (e & 0xffffffff00000000LL);
    }
}

// ---------------- SpMM: sparse [N,512] @ W[512,128] + bias + relu -> bf16 base ----------------

__global__ __launch_bounds__(256) void spmm_feat_kernel(
        const int* __restrict__ row_ptr, const long long* __restrict__ colval,
        const float* __restrict__ W, const float* __restrict__ bias,
        unsigned short* __restrict__ base_bf, int n) {
    const int wave = (blockIdx.x * blockDim.x + threadIdx.x) >> 6;
    const int lane = threadIdx.x & 63;
    if (wave >= n) return;
    const int beg = row_ptr[wave];
    const int end = row_ptr[wave + 1];
    const float2* __restrict__ W2 = (const float2*)W;
    float2 a0 = make_float2(0.f, 0.f), a1 = a0, a2 = a0, a3 = a0;
    int i = beg;
    for (; i + 3 < end; i += 4) {
        int c0, c1, c2, c3; float v0, v1, v2, v3;
        nt_colval(colval + i,     c0, v0);
        nt_colval(colval + i + 1, c1, v1);
        nt_colval(colval + i + 2, c2, v2);
        nt_colval(colval + i + 3, c3, v3);
        const float2 w0 = W2[c0 * 64 + lane];
        const float2 w1 = W2[c1 * 64 + lane];
        const float2 w2 = W2[c2 * 64 + lane];
        const float2 w3 = W2[c3 * 64 + lane];
        a0.x += v0 * w0.x; a0.y += v0 * w0.y;
        a1.x += v1 * w1.x; a1.y += v1 * w1.y;
        a2.x += v2 * w2.x; a2.y += v2 * w2.y;
        a3.x += v3 * w3.x; a3.y += v3 * w3.y;
    }
    for (; i < end; ++i) {
        int c; float v;
        nt_colval(colval + i, c, v);
        const float2 w = W2[c * 64 + lane];
        a0.x += v * w.x; a0.y += v * w.y;
    }
    const float2 b = ((const float2*)bias)[lane];
    float ax = fmaxf((a0.x + a1.x) + (a2.x + a3.x) + b.x, 0.f);
    float ay = fmaxf((a0.y + a1.y) + (a2.y + a3.y) + b.y, 0.f);
    ushort2 o;
    o.x = f2bf(ax);
    o.y = f2bf(ay);
    ((ushort2*)base_bf)[wave * 64 + lane] = o;
}

// ---------------- adjacency pass: dst = A @ src, bf16 in / bf16 out ----------------

__global__ __launch_bounds__(256) void spmm_adj_bf_bf_kernel(
        const int* __restrict__ row_ptr, const long long* __restrict__ colval,
        const unsigned* __restrict__ src, unsigned short* __restrict__ dst, int n) {
    const int wave = (blockIdx.x * blockDim.x + threadIdx.x) >> 6;
    const int lane = threadIdx.x & 63;
    if (wave >= n) return;
    const int beg = row_ptr[wave];
    const int end = row_ptr[wave + 1];
    float2 a0 = make_float2(0.f, 0.f), a1 = a0, a2 = a0, a3 = a0;
    int i = beg;
    for (; i + 3 < end; i += 4) {
        int c0, c1, c2, c3; float v0, v1, v2, v3;
        nt_colval(colval + i,     c0, v0);
        nt_colval(colval + i + 1, c1, v1);
        nt_colval(colval + i + 2, c2, v2);
        nt_colval(colval + i + 3, c3, v3);
        const unsigned s0 = src[c0 * 64 + lane];
        const unsigned s1 = src[c1 * 64 + lane];
        const unsigned s2 = src[c2 * 64 + lane];
        const unsigned s3 = src[c3 * 64 + lane];
        a0.x += v0 * __uint_as_float(s0 << 16); a0.y += v0 * __uint_as_float(s0 & 0xffff0000u);
        a1.x += v1 * __uint_as_float(s1 << 16); a1.y += v1 * __uint_as_float(s1 & 0xffff0000u);
        a2.x += v2 * __uint_as_float(s2 << 16); a2.y += v2 * __uint_as_float(s2 & 0xffff0000u);
        a3.x += v3 * __uint_as_float(s3 << 16); a3.y += v3 * __uint_as_float(s3 & 0xffff0000u);
    }
    for (; i < end; ++i) {
        int c; float v;
        nt_colval(colval + i, c, v);
        const unsigned s = src[c * 64 + lane];
        a0.x += v * __uint_as_float(s << 16); a0.y += v * __uint_as_float(s & 0xffff0000u);
    }
    float ax = (a0.x + a1.x) + (a2.x + a3.x);
    float ay = (a0.y + a1.y) + (a2.y + a3.y);
    ushort2 o;
    o.x = f2bf(ax);
    o.y = f2bf(ay);
    ((ushort2*)dst)[wave * 64 + lane] = o;
}

// ---------------- adjacency pass: dst = A @ src, bf16 in / f32 out ----------------

__global__ __launch_bounds__(256) void spmm_adj_bf_f32_kernel(
        const int* __restrict__ row_ptr, const long long* __restrict__ colval,
        const unsigned* __restrict__ src, float* __restrict__ dst, int n) {
    const int wave = (blockIdx.x * blockDim.x + threadIdx.x) >> 6;
    const int lane = threadIdx.x & 63;
    if (wave >= n) return;
    const int beg = row_ptr[wave];
    const int end = row_ptr[wave + 1];
    float2 a0 = make_float2(0.f, 0.f), a1 = a0, a2 = a0, a3 = a0;
    int i = beg;
    for (; i + 3 < end; i += 4) {
        int c0, c1, c2, c3; float v0, v1, v2, v3;
        nt_colval(colval + i,     c0, v0);
        nt_colval(colval + i + 1, c1, v1);
        nt_colval(colval + i + 2, c2, v2);
        nt_colval(colval + i + 3, c3, v3);
        const unsigned s0 = src[c0 * 64 + lane];
        const unsigned s1 = src[c1 * 64 + lane];
        const unsigned s2 = src[c2 * 64 + lane];
        const unsigned s3 = src[c3 * 64 + lane];
        a0.x += v0 * __uint_as_float(s0 << 16); a0.y += v0 * __uint_as_float(s0 & 0xffff0000u);
        a1.x += v1 * __uint_as_float(s1 << 16); a1.y += v1 * __uint_as_float(s1 & 0xffff0000u);
        a2.x += v2 * __uint_as_float(s2 << 16); a2.y += v2 * __uint_as_float(s2 & 0xffff0000u);
        a3.x += v3 * __uint_as_float(s3 << 16); a3.y += v3 * __uint_as_float(s3 & 0xffff0000u);
    }
    for (; i < end; ++i) {
        int c; float v;
        nt_colval(colval + i, c, v);
        const unsigned s = src[c * 64 + lane];
        a0.x += v * __uint_as_float(s << 16); a0.y += v * __uint_as_float(s & 0xffff0000u);
    }
    float2 acc;
    acc.x = (a0.x + a1.x) + (a2.x + a3.x);
    acc.y = (a0.y + a1.y) + (a2.y + a3.y);
    ((float2*)dst)[wave * 64 + lane] = acc;
}

// ---------------- launch ----------------

extern "C" void kernel_launch(void* const* d_in, const int* in_sizes, int n_in,
                              void* d_out, int out_size, void* d_ws, size_t ws_size,
                              hipStream_t stream) {
    const int*   fi   = (const int*)d_in[0];     // feat_indices [2, nnzf]
    const float* fv   = (const float*)d_in[1];   // feat_values  [nnzf]
    const int*   ai   = (const int*)d_in[2];     // adj_indices  [2, nedge]
    const float* av   = (const float*)d_in[3];   // adj_values   [nedge]
    const float* W    = (const float*)d_in[4];   // weight [512,128]
    const float* bias = (const float*)d_in[5];   // bias [1,128]
    float* out = (float*)d_out;

    const int nnzf  = in_sizes[1];
    const int nedge = in_sizes[3];
    const int ntot  = nnzf + nedge;
    const int* f_rows = fi;
    const int* f_cols = fi + nnzf;
    const int* a_rows = ai;
    const int* a_cols = ai + nedge;

    // bump-allocate workspace (256B aligned)
    char* wp = (char*)d_ws;
    auto balloc = [&](size_t bytes) -> char* {
        char* p = wp;
        wp += (bytes + 255) & ~(size_t)255;
        return p;
    };
    // staging (28.8MB) dead after sort; base_bf (25.6MB) overlays it.
    long long* staging = (long long*)balloc(8ull * (size_t)ntot);
    unsigned short* base_bf = (unsigned short*)staging;
    unsigned short* t1 = (unsigned short*)balloc(2ull * N_NODES * 128);
    long long* colval = (long long*)balloc(8ull * (size_t)ntot);
    int* rp    = (int*)balloc(4ull * (VROWS + 1));
    int* cur   = (int*)balloc(4ull * NBUCK);
    int* bbase = (int*)balloc(4ull * NBUCK);
    int* pbb   = (int*)balloc(4ull * BINB * NBUCK);

    const int RW = (N_NODES + 3) / 4;    // 4 waves (rows) per 256-thread block

    // ---- CSR build: histogram -> scan -> place -> per-bucket sort ----
    zero_small_kernel<<<(NBUCK + 255) / 256, 256, 0, stream>>>(cur, NBUCK);
    binA_kernel<<<BINB, 256, 0, stream>>>(f_rows, a_rows, cur, pbb, nnzf, nedge);
    bucket_scan_kernel<<<1, 1024, 0, stream>>>(cur, bbase, rp);
    binB_kernel<<<BINB, 256, 0, stream>>>(f_rows, f_cols, fv, a_rows, a_cols, av,
                                          bbase, pbb, staging, nnzf, nedge);
    sort_kernel<<<NBUCK, 256, 0, stream>>>(cur, bbase, staging, colval, rp);

    // ---- compute: feat -> base_bf(bf16), adj -> t1(bf16), adj -> out(f32) ----
    spmm_feat_kernel<<<RW, 256, 0, stream>>>(rp, colval, W, bias, base_bf, N_NODES);
    spmm_adj_bf_bf_kernel<<<RW, 256, 0, stream>>>(rp + N_NODES, colval,
                                                  (const unsigned*)base_bf, t1, N_NODES);
    spmm_adj_bf_f32_kernel<<<RW, 256, 0, stream>>>(rp + N_NODES, colval,
                                                   (const unsigned*)t1, out, N_NODES);
}

// Round 9
// 346.568 us; speedup vs baseline: 1.8029x; 1.0828x over previous
//
#include <hip/hip_runtime.h>

#define N_NODES 100000
#define VROWS   200000          // virtual rows: [0,100000)=feat, [100000,200000)=adj
#define BSHIFT  8
#define BROWS   256             // rows per bucket
#define NBUCK   ((VROWS + BROWS - 1) / BROWS)   // 782
#define BINB    256             // blocks for binA/binB

static __device__ __forceinline__ unsigned short f2bf(float x) {
    unsigned u = __float_as_uint(x);
    return (unsigned short)((u + 0x7fffu + ((u >> 16) & 1u)) >> 16);
}
static __device__ __forceinline__ float bf_lo(unsigned u) { return __uint_as_float(u << 16); }
static __device__ __forceinline__ float bf_hi(unsigned u) { return __uint_as_float(u & 0xffff0000u); }

// nt load of a packed (col,val) element via long long (builtin rejects HIP vector types)
static __device__ __forceinline__ void nt_colval(const long long* p, int& c, float& v) {
    long long e = __builtin_nontemporal_load(p);
    c = (int)(e & 0x1ffffLL);
    v = __uint_as_float((unsigned)((unsigned long long)e >> 32));
}

// payload: lo = col(17b) | rowlocal(8b)<<17 ; hi = val bits
static __device__ __forceinline__ long long pack_cv(int col, int rl, float v) {
    unsigned lo = (unsigned)col | ((unsigned)rl << 17);
    return (long long)lo | ((long long)(unsigned)__float_as_uint(v) << 32);
}

// cross-half combine: both halves end with the full sum per output slice
static __device__ __forceinline__ float4 combine_halves(const float4& a0, const float4& a1) {
    float4 a;
    a.x = a0.x + a1.x; a.y = a0.y + a1.y; a.z = a0.z + a1.z; a.w = a0.w + a1.w;
    a.x += __shfl_xor(a.x, 32);
    a.y += __shfl_xor(a.y, 32);
    a.z += __shfl_xor(a.z, 32);
    a.w += __shfl_xor(a.w, 32);
    return a;
}

// ---------------- CSR build: atomic-light two-pass multisplit ----------------

__global__ void zero_small_kernel(int* __restrict__ p, int n) {
    int i = blockIdx.x * blockDim.x + threadIdx.x;
    if (i < n) p[i] = 0;
}

// Pass A: per-block LDS histogram over buckets; ONE global atomic per (block,bucket).
__global__ __launch_bounds__(256) void binA_kernel(
        const int* __restrict__ f_rows, const int* __restrict__ a_rows,
        int* __restrict__ cur, int* __restrict__ pbb, int nnzf, int nedge) {
    __shared__ int hist[NBUCK];
    const int t = threadIdx.x;
    for (int b = t; b < NBUCK; b += 256) hist[b] = 0;
    __syncthreads();
    {
        const int per = (nnzf + BINB - 1) / BINB;
        const int beg = blockIdx.x * per;
        const int end = min(beg + per, nnzf);
        int i = beg + t;
        for (; i + 3 * 256 < end; i += 4 * 256) {
            int r0 = f_rows[i], r1 = f_rows[i + 256], r2 = f_rows[i + 512], r3 = f_rows[i + 768];
            atomicAdd(&hist[r0 >> BSHIFT], 1);
            atomicAdd(&hist[r1 >> BSHIFT], 1);
            atomicAdd(&hist[r2 >> BSHIFT], 1);
            atomicAdd(&hist[r3 >> BSHIFT], 1);
        }
        for (; i < end; i += 256) atomicAdd(&hist[f_rows[i] >> BSHIFT], 1);
    }
    {
        const int per = (nedge + BINB - 1) / BINB;
        const int beg = blockIdx.x * per;
        const int end = min(beg + per, nedge);
        int i = beg + t;
        for (; i + 3 * 256 < end; i += 4 * 256) {
            int r0 = a_rows[i] + N_NODES, r1 = a_rows[i + 256] + N_NODES;
            int r2 = a_rows[i + 512] + N_NODES, r3 = a_rows[i + 768] + N_NODES;
            atomicAdd(&hist[r0 >> BSHIFT], 1);
            atomicAdd(&hist[r1 >> BSHIFT], 1);
            atomicAdd(&hist[r2 >> BSHIFT], 1);
            atomicAdd(&hist[r3 >> BSHIFT], 1);
        }
        for (; i < end; i += 256) atomicAdd(&hist[(a_rows[i] + N_NODES) >> BSHIFT], 1);
    }
    __syncthreads();
    for (int b = t; b < NBUCK; b += 256) {
        int c = hist[b];
        pbb[blockIdx.x * NBUCK + b] = c ? atomicAdd(&cur[b], c) : 0;
    }
}

// Exclusive scan of 782 bucket counts -> bbase; rp[VROWS] = total.
__global__ void bucket_scan_kernel(const int* __restrict__ cur, int* __restrict__ bbase,
                                   int* __restrict__ rp) {
    __shared__ int sh[1024];
    const int t = threadIdx.x;
    int v = (t < NBUCK) ? cur[t] : 0;
    sh[t] = v;
    __syncthreads();
    for (int off = 1; off < 1024; off <<= 1) {
        int u = (t >= off) ? sh[t - off] : 0;
        __syncthreads();
        sh[t] += u;
        __syncthreads();
    }
    if (t < NBUCK) bbase[t] = sh[t] - v;
    if (t == NBUCK - 1) rp[VROWS] = sh[t];
}

// Pass B: replay chunk; place payloads at bbase[b] + pbb[block][b] + ldscursor.
__global__ __launch_bounds__(256) void binB_kernel(
        const int* __restrict__ f_rows, const int* __restrict__ f_cols, const float* __restrict__ f_vals,
        const int* __restrict__ a_rows, const int* __restrict__ a_cols, const float* __restrict__ a_vals,
        const int* __restrict__ bbase, const int* __restrict__ pbb,
        long long* __restrict__ staging, int nnzf, int nedge) {
    __shared__ int curs[NBUCK];
    const int t = threadIdx.x;
    for (int b = t; b < NBUCK; b += 256) curs[b] = bbase[b] + pbb[blockIdx.x * NBUCK + b];
    __syncthreads();
    {
        const int per = (nnzf + BINB - 1) / BINB;
        const int beg = blockIdx.x * per;
        const int end = min(beg + per, nnzf);
        for (int i = beg + t; i < end; i += 256) {
            const int   r = f_rows[i];
            const int   c = f_cols[i];
            const float v = f_vals[i];
            const int p = atomicAdd(&curs[r >> BSHIFT], 1);
            staging[p] = pack_cv(c, r & (BROWS - 1), v);
        }
    }
    {
        const int per = (nedge + BINB - 1) / BINB;
        const int beg = blockIdx.x * per;
        const int end = min(beg + per, nedge);
        for (int i = beg + t; i < end; i += 256) {
            const int   r = a_rows[i] + N_NODES;
            const int   c = a_cols[i];
            const float v = a_vals[i];
            const int p = atomicAdd(&curs[r >> BSHIFT], 1);
            staging[p] = pack_cv(c, r & (BROWS - 1), v);
        }
    }
}

// Per-bucket sort: count rows in LDS -> scan -> row_ptr -> place into colval.
__global__ __launch_bounds__(256) void sort_kernel(
        const int* __restrict__ cur, const int* __restrict__ bbase,
        const long long* __restrict__ staging, long long* __restrict__ colval,
        int* __restrict__ rp) {
    const int b = blockIdx.x;
    const int t = threadIdx.x;
    __shared__ int cnt[BROWS];
    __shared__ int offs[BROWS];
    cnt[t] = 0;
    __syncthreads();
    const int n = cur[b];
    const int base = bbase[b];
    const long long* seg = staging + base;
    for (int j = t; j < n; j += 256) {
        unsigned lo = (unsigned)(seg[j] & 0xffffffffLL);
        atomicAdd(&cnt[(lo >> 17) & (BROWS - 1)], 1);
    }
    __syncthreads();
    int v = cnt[t];
    offs[t] = v;
    __syncthreads();
    for (int o = 1; o < BROWS; o <<= 1) {
        int u = (t >= o) ? offs[t - o] : 0;
        __syncthreads();
        offs[t] += u;
        __syncthreads();
    }
    const int excl = offs[t] - v;
    offs[t] = base + excl;           // absolute placement cursor
    const int row = (b << BSHIFT) + t;
    if (row < VROWS) rp[row] = base + excl;
    __syncthreads();
    for (int j = t; j < n; j += 256) {
        long long e = seg[j];
        unsigned lo = (unsigned)(e & 0xffffffffLL);
        const int rl = (lo >> 17) & (BROWS - 1);
        const int p = atomicAdd(&offs[rl], 1);
        colval[p] = (long long)(lo & 0x1ffffu) | (e & 0xffffffff00000000LL);
    }
}

// ---------------- SpMM feat: half-wave pair split ----------------
// Lanes 0-31 process even elements, lanes 32-63 odd; each lane covers outputs
// [4s,4s+4) via one float4 W load. Combine halves with shfl_xor(32) at the end.

__global__ __launch_bounds__(256) void spmm_feat_kernel(
        const int* __restrict__ row_ptr, const long long* __restrict__ colval,
        const float* __restrict__ W, const float* __restrict__ bias,
        unsigned short* __restrict__ base_bf, int n) {
    const int wave = (blockIdx.x * blockDim.x + threadIdx.x) >> 6;
    const int lane = threadIdx.x & 63;
    const int h = lane >> 5;
    const int s = lane & 31;
    if (wave >= n) return;
    const int beg = row_ptr[wave];
    const int end = row_ptr[wave + 1];
    const float4* __restrict__ W4 = (const float4*)W;
    float4 a0 = make_float4(0.f, 0.f, 0.f, 0.f), a1 = a0;
    int i = beg;
    for (; i + 3 < end; i += 4) {
        int c0, c1; float v0, v1;
        nt_colval(colval + i + h,     c0, v0);
        nt_colval(colval + i + 2 + h, c1, v1);
        const float4 w0 = W4[c0 * 32 + s];
        const float4 w1 = W4[c1 * 32 + s];
        a0.x += v0 * w0.x; a0.y += v0 * w0.y; a0.z += v0 * w0.z; a0.w += v0 * w0.w;
        a1.x += v1 * w1.x; a1.y += v1 * w1.y; a1.z += v1 * w1.z; a1.w += v1 * w1.w;
    }
    for (; i + 1 < end; i += 2) {
        int c; float v;
        nt_colval(colval + i + h, c, v);
        const float4 w = W4[c * 32 + s];
        a0.x += v * w.x; a0.y += v * w.y; a0.z += v * w.z; a0.w += v * w.w;
    }
    if (i < end) {
        int c; float v;
        nt_colval(colval + i, c, v);
        if (h) v = 0.f;
        const float4 w = W4[c * 32 + s];
        a0.x += v * w.x; a0.y += v * w.y; a0.z += v * w.z; a0.w += v * w.w;
    }
    float4 acc = combine_halves(a0, a1);
    if (h == 0) {
        const float4 b = ((const float4*)bias)[s];
        ushort4 o;
        o.x = f2bf(fmaxf(acc.x + b.x, 0.f));
        o.y = f2bf(fmaxf(acc.y + b.y, 0.f));
        o.z = f2bf(fmaxf(acc.z + b.z, 0.f));
        o.w = f2bf(fmaxf(acc.w + b.w, 0.f));
        ((ushort4*)(base_bf + (size_t)wave * 128))[s] = o;
    }
}

// ---------------- adjacency pass: bf16 in / bf16 out, pair split ----------------

__global__ __launch_bounds__(256) void spmm_adj_bf_bf_kernel(
        const int* __restrict__ row_ptr, const long long* __restrict__ colval,
        const uint2* __restrict__ src, unsigned short* __restrict__ dst, int n) {
    const int wave = (blockIdx.x * blockDim.x + threadIdx.x) >> 6;
    const int lane = threadIdx.x & 63;
    const int h = lane >> 5;
    const int s = lane & 31;
    if (wave >= n) return;
    const int beg = row_ptr[wave];
    const int end = row_ptr[wave + 1];
    float4 a0 = make_float4(0.f, 0.f, 0.f, 0.f), a1 = a0;
    int i = beg;
    for (; i + 3 < end; i += 4) {
        int c0, c1; float v0, v1;
        nt_colval(colval + i + h,     c0, v0);
        nt_colval(colval + i + 2 + h, c1, v1);
        const uint2 u0 = src[c0 * 32 + s];
        const uint2 u1 = src[c1 * 32 + s];
        a0.x += v0 * bf_lo(u0.x); a0.y += v0 * bf_hi(u0.x);
        a0.z += v0 * bf_lo(u0.y); a0.w += v0 * bf_hi(u0.y);
        a1.x += v1 * bf_lo(u1.x); a1.y += v1 * bf_hi(u1.x);
        a1.z += v1 * bf_lo(u1.y); a1.w += v1 * bf_hi(u1.y);
    }
    for (; i + 1 < end; i += 2) {
        int c; float v;
        nt_colval(colval + i + h, c, v);
        const uint2 u = src[c * 32 + s];
        a0.x += v * bf_lo(u.x); a0.y += v * bf_hi(u.x);
        a0.z += v * bf_lo(u.y); a0.w += v * bf_hi(u.y);
    }
    if (i < end) {
        int c; float v;
        nt_colval(colval + i, c, v);
        if (h) v = 0.f;
        const uint2 u = src[c * 32 + s];
        a0.x += v * bf_lo(u.x); a0.y += v * bf_hi(u.x);
        a0.z += v * bf_lo(u.y); a0.w += v * bf_hi(u.y);
    }
    float4 acc = combine_halves(a0, a1);
    if (h == 0) {
        ushort4 o;
        o.x = f2bf(acc.x); o.y = f2bf(acc.y); o.z = f2bf(acc.z); o.w = f2bf(acc.w);
        ((ushort4*)(dst + (size_t)wave * 128))[s] = o;
    }
}

// ---------------- adjacency pass: bf16 in / f32 out, pair split ----------------

__global__ __launch_bounds__(256) void spmm_adj_bf_f32_kernel(
        const int* __restrict__ row_ptr, const long long* __restrict__ colval,
        const uint2* __restrict__ src, float* __restrict__ dst, int n) {
    const int wave = (blockIdx.x * blockDim.x + threadIdx.x) >> 6;
    const int lane = threadIdx.x & 63;
    const int h = lane >> 5;
    const int s = lane & 31;
    if (wave >= n) return;
    const int beg = row_ptr[wave];
    const int end = row_ptr[wave + 1];
    float4 a0 = make_float4(0.f, 0.f, 0.f, 0.f), a1 = a0;
    int i = beg;
    for (; i + 3 < end; i += 4) {
        int c0, c1; float v0, v1;
        nt_colval(colval + i + h,     c0, v0);
        nt_colval(colval + i + 2 + h, c1, v1);
        const uint2 u0 = src[c0 * 32 + s];
        const uint2 u1 = src[c1 * 32 + s];
        a0.x += v0 * bf_lo(u0.x); a0.y += v0 * bf_hi(u0.x);
        a0.z += v0 * bf_lo(u0.y); a0.w += v0 * bf_hi(u0.y);
        a1.x += v1 * bf_lo(u1.x); a1.y += v1 * bf_hi(u1.x);
        a1.z += v1 * bf_lo(u1.y); a1.w += v1 * bf_hi(u1.y);
    }
    for (; i + 1 < end; i += 2) {
        int c; float v;
        nt_colval(colval + i + h, c, v);
        const uint2 u = src[c * 32 + s];
        a0.x += v * bf_lo(u.x); a0.y += v * bf_hi(u.x);
        a0.z += v * bf_lo(u.y); a0.w += v * bf_hi(u.y);
    }
    if (i < end) {
        int c; float v;
        nt_colval(colval + i, c, v);
        if (h) v = 0.f;
        const uint2 u = src[c * 32 + s];
        a0.x += v * bf_lo(u.x); a0.y += v * bf_hi(u.x);
        a0.z += v * bf_lo(u.y); a0.w += v * bf_hi(u.y);
    }
    float4 acc = combine_halves(a0, a1);
    if (h == 0) {
        ((float4*)(dst + (size_t)wave * 128))[s] = acc;
    }
}

// ---------------- launch ----------------

extern "C" void kernel_launch(void* const* d_in, const int* in_sizes, int n_in,
                              void* d_out, int out_size, void* d_ws, size_t ws_size,
                              hipStream_t stream) {
    const int*   fi   = (const int*)d_in[0];     // feat_indices [2, nnzf]
    const float* fv   = (const float*)d_in[1];   // feat_values  [nnzf]
    const int*   ai   = (const int*)d_in[2];     // adj_indices  [2, nedge]
    const float* av   = (const float*)d_in[3];   // adj_values   [nedge]
    const float* W    = (const float*)d_in[4];   // weight [512,128]
    const float* bias = (const float*)d_in[5];   // bias [1,128]
    float* out = (float*)d_out;

    const int nnzf  = in_sizes[1];
    const int nedge = in_sizes[3];
    const int ntot  = nnzf + nedge;
    const int* f_rows = fi;
    const int* f_cols = fi + nnzf;
    const int* a_rows = ai;
    const int* a_cols = ai + nedge;

    // bump-allocate workspace (256B aligned)
    char* wp = (char*)d_ws;
    auto balloc = [&](size_t bytes) -> char* {
        char* p = wp;
        wp += (bytes + 255) & ~(size_t)255;
        return p;
    };
    // staging (28.8MB) dead after sort; base_bf (25.6MB) overlays it.
    long long* staging = (long long*)balloc(8ull * (size_t)ntot);
    unsigned short* base_bf = (unsigned short*)staging;
    unsigned short* t1 = (unsigned short*)balloc(2ull * N_NODES * 128);
    long long* colval = (long long*)balloc(8ull * (size_t)ntot);
    int* rp    = (int*)balloc(4ull * (VROWS + 1));
    int* cur   = (int*)balloc(4ull * NBUCK);
    int* bbase = (int*)balloc(4ull * NBUCK);
    int* pbb   = (int*)balloc(4ull * BINB * NBUCK);

    const int RW = (N_NODES + 3) / 4;    // 4 waves (rows) per 256-thread block

    // ---- CSR build: histogram -> scan -> place -> per-bucket sort ----
    zero_small_kernel<<<(NBUCK + 255) / 256, 256, 0, stream>>>(cur, NBUCK);
    binA_kernel<<<BINB, 256, 0, stream>>>(f_rows, a_rows, cur, pbb, nnzf, nedge);
    bucket_scan_kernel<<<1, 1024, 0, stream>>>(cur, bbase, rp);
    binB_kernel<<<BINB, 256, 0, stream>>>(f_rows, f_cols, fv, a_rows, a_cols, av,
                                          bbase, pbb, staging, nnzf, nedge);
    sort_kernel<<<NBUCK, 256, 0, stream>>>(cur, bbase, staging, colval, rp);

    // ---- compute: feat -> base_bf(bf16), adj -> t1(bf16), adj -> out(f32) ----
    spmm_feat_kernel<<<RW, 256, 0, stream>>>(rp, colval, W, bias, base_bf, N_NODES);
    spmm_adj_bf_bf_kernel<<<RW, 256, 0, stream>>>(rp + N_NODES, colval,
                                                  (const uint2*)base_bf, t1, N_NODES);
    spmm_adj_bf_f32_kernel<<<RW, 256, 0, stream>>>(rp + N_NODES, colval,
                                                   (const uint2*)t1, out, N_NODES);
}

// Round 10
// 335.762 us; speedup vs baseline: 1.8609x; 1.0322x over previous
//
#include <hip/hip_runtime.h>

#define N_NODES 100000
#define VROWS   200000          // virtual rows: [0,100000)=feat, [100000,200000)=adj
#define BSHIFT  8
#define BROWS   256             // rows per bucket
#define NBUCK   ((VROWS + BROWS - 1) / BROWS)   // 782
#define BINB    256             // blocks for binA/binB

static __device__ __forceinline__ unsigned short f2bf(float x) {
    unsigned u = __float_as_uint(x);
    return (unsigned short)((u + 0x7fffu + ((u >> 16) & 1u)) >> 16);
}
static __device__ __forceinline__ float bf_lo(unsigned u) { return __uint_as_float(u << 16); }
static __device__ __forceinline__ float bf_hi(unsigned u) { return __uint_as_float(u & 0xffff0000u); }

// nt load of a packed (col,val) element via long long (builtin rejects HIP vector types)
static __device__ __forceinline__ void nt_colval(const long long* p, int& c, float& v) {
    long long e = __builtin_nontemporal_load(p);
    c = (int)(e & 0x1ffffLL);
    v = __uint_as_float((unsigned)((unsigned long long)e >> 32));
}

// payload: lo = col(17b) | rowlocal(8b)<<17 ; hi = val bits
static __device__ __forceinline__ long long pack_cv(int col, int rl, float v) {
    unsigned lo = (unsigned)col | ((unsigned)rl << 17);
    return (long long)lo | ((long long)(unsigned)__float_as_uint(v) << 32);
}

// ---------------- CSR build: atomic-light two-pass multisplit ----------------

__global__ void zero_small_kernel(int* __restrict__ p, int n) {
    int i = blockIdx.x * blockDim.x + threadIdx.x;
    if (i < n) p[i] = 0;
}

// Pass A: per-block LDS histogram over buckets; ONE global atomic per (block,bucket).
__global__ __launch_bounds__(256) void binA_kernel(
        const int* __restrict__ f_rows, const int* __restrict__ a_rows,
        int* __restrict__ cur, int* __restrict__ pbb, int nnzf, int nedge) {
    __shared__ int hist[NBUCK];
    const int t = threadIdx.x;
    for (int b = t; b < NBUCK; b += 256) hist[b] = 0;
    __syncthreads();
    {
        const int per = (nnzf + BINB - 1) / BINB;
        const int beg = blockIdx.x * per;
        const int end = min(beg + per, nnzf);
        int i = beg + t;
        for (; i + 3 * 256 < end; i += 4 * 256) {
            int r0 = f_rows[i], r1 = f_rows[i + 256], r2 = f_rows[i + 512], r3 = f_rows[i + 768];
            atomicAdd(&hist[r0 >> BSHIFT], 1);
            atomicAdd(&hist[r1 >> BSHIFT], 1);
            atomicAdd(&hist[r2 >> BSHIFT], 1);
            atomicAdd(&hist[r3 >> BSHIFT], 1);
        }
        for (; i < end; i += 256) atomicAdd(&hist[f_rows[i] >> BSHIFT], 1);
    }
    {
        const int per = (nedge + BINB - 1) / BINB;
        const int beg = blockIdx.x * per;
        const int end = min(beg + per, nedge);
        int i = beg + t;
        for (; i + 3 * 256 < end; i += 4 * 256) {
            int r0 = a_rows[i] + N_NODES, r1 = a_rows[i + 256] + N_NODES;
            int r2 = a_rows[i + 512] + N_NODES, r3 = a_rows[i + 768] + N_NODES;
            atomicAdd(&hist[r0 >> BSHIFT], 1);
            atomicAdd(&hist[r1 >> BSHIFT], 1);
            atomicAdd(&hist[r2 >> BSHIFT], 1);
            atomicAdd(&hist[r3 >> BSHIFT], 1);
        }
        for (; i < end; i += 256) atomicAdd(&hist[(a_rows[i] + N_NODES) >> BSHIFT], 1);
    }
    __syncthreads();
    for (int b = t; b < NBUCK; b += 256) {
        int c = hist[b];
        pbb[blockIdx.x * NBUCK + b] = c ? atomicAdd(&cur[b], c) : 0;
    }
}

// Exclusive scan of 782 bucket counts -> bbase; rp[VROWS] = total.
__global__ void bucket_scan_kernel(const int* __restrict__ cur, int* __restrict__ bbase,
                                   int* __restrict__ rp) {
    __shared__ int sh[1024];
    const int t = threadIdx.x;
    int v = (t < NBUCK) ? cur[t] : 0;
    sh[t] = v;
    __syncthreads();
    for (int off = 1; off < 1024; off <<= 1) {
        int u = (t >= off) ? sh[t - off] : 0;
        __syncthreads();
        sh[t] += u;
        __syncthreads();
    }
    if (t < NBUCK) bbase[t] = sh[t] - v;
    if (t == NBUCK - 1) rp[VROWS] = sh[t];
}

// Pass B: replay chunk; place payloads at bbase[b] + pbb[block][b] + ldscursor.
__global__ __launch_bounds__(256) void binB_kernel(
        const int* __restrict__ f_rows, const int* __restrict__ f_cols, const float* __restrict__ f_vals,
        const int* __restrict__ a_rows, const int* __restrict__ a_cols, const float* __restrict__ a_vals,
        const int* __restrict__ bbase, const int* __restrict__ pbb,
        long long* __restrict__ staging, int nnzf, int nedge) {
    __shared__ int curs[NBUCK];
    const int t = threadIdx.x;
    for (int b = t; b < NBUCK; b += 256) curs[b] = bbase[b] + pbb[blockIdx.x * NBUCK + b];
    __syncthreads();
    {
        const int per = (nnzf + BINB - 1) / BINB;
        const int beg = blockIdx.x * per;
        const int end = min(beg + per, nnzf);
        for (int i = beg + t; i < end; i += 256) {
            const int   r = f_rows[i];
            const int   c = f_cols[i];
            const float v = f_vals[i];
            const int p = atomicAdd(&curs[r >> BSHIFT], 1);
            staging[p] = pack_cv(c, r & (BROWS - 1), v);
        }
    }
    {
        const int per = (nedge + BINB - 1) / BINB;
        const int beg = blockIdx.x * per;
        const int end = min(beg + per, nedge);
        for (int i = beg + t; i < end; i += 256) {
            const int   r = a_rows[i] + N_NODES;
            const int   c = a_cols[i];
            const float v = a_vals[i];
            const int p = atomicAdd(&curs[r >> BSHIFT], 1);
            staging[p] = pack_cv(c, r & (BROWS - 1), v);
        }
    }
}

// Per-bucket sort: count rows in LDS -> scan -> row_ptr -> place into colval.
__global__ __launch_bounds__(256) void sort_kernel(
        const int* __restrict__ cur, const int* __restrict__ bbase,
        const long long* __restrict__ staging, long long* __restrict__ colval,
        int* __restrict__ rp) {
    const int b = blockIdx.x;
    const int t = threadIdx.x;
    __shared__ int cnt[BROWS];
    __shared__ int offs[BROWS];
    cnt[t] = 0;
    __syncthreads();
    const int n = cur[b];
    const int base = bbase[b];
    const long long* seg = staging + base;
    for (int j = t; j < n; j += 256) {
        unsigned lo = (unsigned)(seg[j] & 0xffffffffLL);
        atomicAdd(&cnt[(lo >> 17) & (BROWS - 1)], 1);
    }
    __syncthreads();
    int v = cnt[t];
    offs[t] = v;
    __syncthreads();
    for (int o = 1; o < BROWS; o <<= 1) {
        int u = (t >= o) ? offs[t - o] : 0;
        __syncthreads();
        offs[t] += u;
        __syncthreads();
    }
    const int excl = offs[t] - v;
    offs[t] = base + excl;           // absolute placement cursor
    const int row = (b << BSHIFT) + t;
    if (row < VROWS) rp[row] = base + excl;
    __syncthreads();
    for (int j = t; j < n; j += 256) {
        long long e = seg[j];
        unsigned lo = (unsigned)(e & 0xffffffffLL);
        const int rl = (lo >> 17) & (BROWS - 1);
        const int p = atomicAdd(&offs[rl], 1);
        colval[p] = (long long)(lo & 0x1ffffu) | (e & 0xffffffff00000000LL);
    }
}

// ---------------- SpMM feat: one row per 32-lane half-wave ----------------
// Each half covers all 128 outputs (32 lanes x float4); 2-way unroll gives the
// wave 4 independent colval->W load chains. No cross-half combine needed.

__global__ __launch_bounds__(256) void spmm_feat_kernel(
        const int* __restrict__ row_ptr, const long long* __restrict__ colval,
        const float* __restrict__ W, const float* __restrict__ bias,
        unsigned short* __restrict__ base_bf, int n) {
    const int wave = (blockIdx.x * blockDim.x + threadIdx.x) >> 6;
    const int lane = threadIdx.x & 63;
    const int h = lane >> 5;
    const int s = lane & 31;
    const int r = wave * 2 + h;
    const float4* __restrict__ W4 = (const float4*)W;
    float4 a0 = make_float4(0.f, 0.f, 0.f, 0.f), a1 = a0;
    int i = 0, end = 0;
    if (r < n) { i = row_ptr[r]; end = row_ptr[r + 1]; }
    for (; i + 1 < end; i += 2) {
        int c0, c1; float v0, v1;
        nt_colval(colval + i,     c0, v0);
        nt_colval(colval + i + 1, c1, v1);
        const float4 w0 = W4[c0 * 32 + s];
        const float4 w1 = W4[c1 * 32 + s];
        a0.x += v0 * w0.x; a0.y += v0 * w0.y; a0.z += v0 * w0.z; a0.w += v0 * w0.w;
        a1.x += v1 * w1.x; a1.y += v1 * w1.y; a1.z += v1 * w1.z; a1.w += v1 * w1.w;
    }
    if (i < end) {
        int c; float v;
        nt_colval(colval + i, c, v);
        const float4 w = W4[c * 32 + s];
        a0.x += v * w.x; a0.y += v * w.y; a0.z += v * w.z; a0.w += v * w.w;
    }
    if (r < n) {
        const float4 b = ((const float4*)bias)[s];
        ushort4 o;
        o.x = f2bf(fmaxf(a0.x + a1.x + b.x, 0.f));
        o.y = f2bf(fmaxf(a0.y + a1.y + b.y, 0.f));
        o.z = f2bf(fmaxf(a0.z + a1.z + b.z, 0.f));
        o.w = f2bf(fmaxf(a0.w + a1.w + b.w, 0.f));
        ((ushort4*)(base_bf + (size_t)r * 128))[s] = o;
    }
}

// ---------------- adjacency pass: bf16 in / bf16 out, row-per-half ----------------

__global__ __launch_bounds__(256) void spmm_adj_bf_bf_kernel(
        const int* __restrict__ row_ptr, const long long* __restrict__ colval,
        const uint2* __restrict__ src, unsigned short* __restrict__ dst, int n) {
    const int wave = (blockIdx.x * blockDim.x + threadIdx.x) >> 6;
    const int lane = threadIdx.x & 63;
    const int h = lane >> 5;
    const int s = lane & 31;
    const int r = wave * 2 + h;
    float4 a0 = make_float4(0.f, 0.f, 0.f, 0.f), a1 = a0;
    int i = 0, end = 0;
    if (r < n) { i = row_ptr[r]; end = row_ptr[r + 1]; }
    for (; i + 1 < end; i += 2) {
        int c0, c1; float v0, v1;
        nt_colval(colval + i,     c0, v0);
        nt_colval(colval + i + 1, c1, v1);
        const uint2 u0 = src[c0 * 32 + s];
        const uint2 u1 = src[c1 * 32 + s];
        a0.x += v0 * bf_lo(u0.x); a0.y += v0 * bf_hi(u0.x);
        a0.z += v0 * bf_lo(u0.y); a0.w += v0 * bf_hi(u0.y);
        a1.x += v1 * bf_lo(u1.x); a1.y += v1 * bf_hi(u1.x);
        a1.z += v1 * bf_lo(u1.y); a1.w += v1 * bf_hi(u1.y);
    }
    if (i < end) {
        int c; float v;
        nt_colval(colval + i, c, v);
        const uint2 u = src[c * 32 + s];
        a0.x += v * bf_lo(u.x); a0.y += v * bf_hi(u.x);
        a0.z += v * bf_lo(u.y); a0.w += v * bf_hi(u.y);
    }
    if (r < n) {
        ushort4 o;
        o.x = f2bf(a0.x + a1.x); o.y = f2bf(a0.y + a1.y);
        o.z = f2bf(a0.z + a1.z); o.w = f2bf(a0.w + a1.w);
        ((ushort4*)(dst + (size_t)r * 128))[s] = o;
    }
}

// ---------------- adjacency pass: bf16 in / f32 out, row-per-half ----------------

__global__ __launch_bounds__(256) void spmm_adj_bf_f32_kernel(
        const int* __restrict__ row_ptr, const long long* __restrict__ colval,
        const uint2* __restrict__ src, float* __restrict__ dst, int n) {
    const int wave = (blockIdx.x * blockDim.x + threadIdx.x) >> 6;
    const int lane = threadIdx.x & 63;
    const int h = lane >> 5;
    const int s = lane & 31;
    const int r = wave * 2 + h;
    float4 a0 = make_float4(0.f, 0.f, 0.f, 0.f), a1 = a0;
    int i = 0, end = 0;
    if (r < n) { i = row_ptr[r]; end = row_ptr[r + 1]; }
    for (; i + 1 < end; i += 2) {
        int c0, c1; float v0, v1;
        nt_colval(colval + i,     c0, v0);
        nt_colval(colval + i + 1, c1, v1);
        const uint2 u0 = src[c0 * 32 + s];
        const uint2 u1 = src[c1 * 32 + s];
        a0.x += v0 * bf_lo(u0.x); a0.y += v0 * bf_hi(u0.x);
        a0.z += v0 * bf_lo(u0.y); a0.w += v0 * bf_hi(u0.y);
        a1.x += v1 * bf_lo(u1.x); a1.y += v1 * bf_hi(u1.x);
        a1.z += v1 * bf_lo(u1.y); a1.w += v1 * bf_hi(u1.y);
    }
    if (i < end) {
        int c; float v;
        nt_colval(colval + i, c, v);
        const uint2 u = src[c * 32 + s];
        a0.x += v * bf_lo(u.x); a0.y += v * bf_hi(u.x);
        a0.z += v * bf_lo(u.y); a0.w += v * bf_hi(u.y);
    }
    if (r < n) {
        float4 acc;
        acc.x = a0.x + a1.x; acc.y = a0.y + a1.y;
        acc.z = a0.z + a1.z; acc.w = a0.w + a1.w;
        ((float4*)(dst + (size_t)r * 128))[s] = acc;
    }
}

// ---------------- launch ----------------

extern "C" void kernel_launch(void* const* d_in, const int* in_sizes, int n_in,
                              void* d_out, int out_size, void* d_ws, size_t ws_size,
                              hipStream_t stream) {
    const int*   fi   = (const int*)d_in[0];     // feat_indices [2, nnzf]
    const float* fv   = (const float*)d_in[1];   // feat_values  [nnzf]
    const int*   ai   = (const int*)d_in[2];     // adj_indices  [2, nedge]
    const float* av   = (const float*)d_in[3];   // adj_values   [nedge]
    const float* W    = (const float*)d_in[4];   // weight [512,128]
    const float* bias = (const float*)d_in[5];   // bias [1,128]
    float* out = (float*)d_out;

    const int nnzf  = in_sizes[1];
    const int nedge = in_sizes[3];
    const int ntot  = nnzf + nedge;
    const int* f_rows = fi;
    const int* f_cols = fi + nnzf;
    const int* a_rows = ai;
    const int* a_cols = ai + nedge;

    // bump-allocate workspace (256B aligned)
    char* wp = (char*)d_ws;
    auto balloc = [&](size_t bytes) -> char* {
        char* p = wp;
        wp += (bytes + 255) & ~(size_t)255;
        return p;
    };
    // staging (28.8MB) dead after sort; base_bf (25.6MB) overlays it.
    long long* staging = (long long*)balloc(8ull * (size_t)ntot);
    unsigned short* base_bf = (unsigned short*)staging;
    unsigned short* t1 = (unsigned short*)balloc(2ull * N_NODES * 128);
    long long* colval = (long long*)balloc(8ull * (size_t)ntot);
    int* rp    = (int*)balloc(4ull * (VROWS + 1));
    int* cur   = (int*)balloc(4ull * NBUCK);
    int* bbase = (int*)balloc(4ull * NBUCK);
    int* pbb   = (int*)balloc(4ull * BINB * NBUCK);

    const int nwaves = (N_NODES + 1) / 2;          // 2 rows per wave
    const int RW = (nwaves + 3) / 4;               // 4 waves per 256-thread block

    // ---- CSR build: histogram -> scan -> place -> per-bucket sort ----
    zero_small_kernel<<<(NBUCK + 255) / 256, 256, 0, stream>>>(cur, NBUCK);
    binA_kernel<<<BINB, 256, 0, stream>>>(f_rows, a_rows, cur, pbb, nnzf, nedge);
    bucket_scan_kernel<<<1, 1024, 0, stream>>>(cur, bbase, rp);
    binB_kernel<<<BINB, 256, 0, stream>>>(f_rows, f_cols, fv, a_rows, a_cols, av,
                                          bbase, pbb, staging, nnzf, nedge);
    sort_kernel<<<NBUCK, 256, 0, stream>>>(cur, bbase, staging, colval, rp);

    // ---- compute: feat -> base_bf(bf16), adj -> t1(bf16), adj -> out(f32) ----
    spmm_feat_kernel<<<RW, 256, 0, stream>>>(rp, colval, W, bias, base_bf, N_NODES);
    spmm_adj_bf_bf_kernel<<<RW, 256, 0, stream>>>(rp + N_NODES, colval,
                                                  (const uint2*)base_bf, t1, N_NODES);
    spmm_adj_bf_f32_kernel<<<RW, 256, 0, stream>>>(rp + N_NODES, colval,
                                                   (const uint2*)t1, out, N_NODES);
}